// Round 5
// baseline (20720.940 us; speedup 1.0000x reference)
//
#include <hip/hip_runtime.h>
#include <math.h>

// Problem constants
#define EMBD 400
#define HIDD 300
#define KEYD 128
#define VALD 128
#define NVOC 33
#define TT 256
#define BB 256
#define SS 512
#define WIH_LD 528          // EMB+VAL
#define GDIM 1200           // 4*HID
#define KTOT 428            // ctx(128)+h(300)
#define NJT 75              // gates j-tiles (1200/16)
#define NKT 14              // gates k-tiles (448/32): kt0-3 ctx, kt4-13 h
#define NBLK 256            // one block per batch row

typedef unsigned short u16;
typedef unsigned int u32x4 __attribute__((ext_vector_type(4)));
typedef unsigned int u32x2 __attribute__((ext_vector_type(2)));
typedef short bf16x8 __attribute__((ext_vector_type(8)));
typedef float f32x4 __attribute__((ext_vector_type(4)));

__device__ __forceinline__ f32x4 mfma16(bf16x8 a, bf16x8 b, f32x4 c) {
    return __builtin_amdgcn_mfma_f32_16x16x32_bf16(a, b, c, 0, 0, 0);
}
__device__ __forceinline__ float bflo(unsigned int u) {
    return __uint_as_float(u << 16);
}
__device__ __forceinline__ float bfhi(unsigned int u) {
    return __uint_as_float(u & 0xffff0000u);
}
__device__ __forceinline__ u16 f2bf(float x) {   // RNE, no NaN inputs
    unsigned int u = __float_as_uint(x);
    return (u16)((u + 0x7fffu + ((u >> 16) & 1u)) >> 16);
}
__device__ __forceinline__ float bf2f(u16 h) {
    return __uint_as_float(((unsigned int)h) << 16);
}
__device__ __forceinline__ void bf2term(float x, u16& hi, u16& lo) {
    hi = f2bf(x);
    lo = f2bf(x - bf2f(hi));
}
__device__ __forceinline__ float sigmoidf_(float x) {
    return 1.f / (1.f + __expf(-x));
}
__device__ __forceinline__ float tanh_f(float x) {
    float ax = fabsf(x);
    if (ax > 15.f) return x > 0.f ? 1.f : -1.f;
    float e = __expf(2.f * x);
    return (e - 1.f) / (e + 1.f);
}

// ---------------- Precompute: E2[v][j] = b_ih[j]+b_hh[j]+emb[v]·W_ih[j][:400]
__global__ __launch_bounds__(256) void p_e2(
    const float* __restrict__ emb, const float* __restrict__ Wih,
    const float* __restrict__ bih, const float* __restrict__ bhh,
    float* __restrict__ E2)
{
    __shared__ float es[EMBD];
    const int v = blockIdx.x;
    for (int i = threadIdx.x; i < EMBD; i += 256) es[i] = emb[v * EMBD + i];
    __syncthreads();
    for (int j = threadIdx.x; j < GDIM; j += 256) {
        const float* wr = &Wih[(size_t)j * WIH_LD];
        float s0 = 0.f, s1 = 0.f, s2 = 0.f, s3 = 0.f;
        for (int e = 0; e < EMBD; e += 4) {
            s0 += es[e]     * wr[e];
            s1 += es[e + 1] * wr[e + 1];
            s2 += es[e + 2] * wr[e + 2];
            s3 += es[e + 3] * wr[e + 3];
        }
        E2[v * GDIM + j] = bih[j] + bhh[j] + ((s0 + s1) + (s2 + s3));
    }
}

// ---------------- Precompute: Wtb -> MFMA B-frag tiles; phi -> hi/lo B-frags
// B-frag 16x16x32: lane l holds B[k=(l>>4)*8+e][col=l&15], element lane*8+e.
__global__ __launch_bounds__(256) void p_wt(
    const float* __restrict__ Wih, const float* __restrict__ Whh,
    const float* __restrict__ phi_w,
    u16* __restrict__ Wtbf, u16* __restrict__ phiH, u16* __restrict__ phiL)
{
    const int stride = gridDim.x * 256;
    const int tot1 = NJT * NKT * 512;
    for (int i = blockIdx.x * 256 + threadIdx.x; i < tot1; i += stride) {
        int tile = i >> 9, rem = i & 511;
        int lane = rem >> 3, e = rem & 7;
        int jt = tile / NKT, kt = tile - jt * NKT;
        int k = kt * 32 + ((lane >> 4) << 3) + e;
        int j = jt * 16 + (lane & 15);
        float v = 0.f;
        if (k < KEYD)      v = Wih[(size_t)j * WIH_LD + EMBD + k];
        else if (k < KTOT) v = Whh[(size_t)j * HIDD + (k - KEYD)];
        Wtbf[i] = f2bf(v);
    }
    const int tot2 = 8 * 10 * 512;   // qt x it tiles
    for (int i = blockIdx.x * 256 + threadIdx.x; i < tot2; i += stride) {
        int tile = i >> 9, rem = i & 511;
        int lane = rem >> 3, e = rem & 7;
        int qt = tile / 10, it = tile - qt * 10;
        int ii = it * 32 + ((lane >> 4) << 3) + e;
        int kc = qt * 16 + (lane & 15);
        float v = (ii < HIDD) ? phi_w[(size_t)kc * HIDD + ii] : 0.f;
        u16 h_, l_;
        bf2term(v, h_, l_);
        phiH[i] = h_; phiL[i] = l_;
    }
}

// ---------------- Precompute: KV -> bf16, transposed to [b][s][dim]
__global__ __launch_bounds__(1024) void p_kv(
    const float* __restrict__ keys, const float* __restrict__ values,
    u16* __restrict__ kbf, u16* __restrict__ vbf)
{
    size_t i = (size_t)blockIdx.x * 1024 + threadIdx.x;  // S*B*K total exactly
    int s = (int)(i >> 15);
    int r = (int)(i & 32767);
    int b = r >> 7, k = r & 127;
    size_t d = (((size_t)b * SS + s) << 7) + k;
    kbf[d] = f2bf(keys[i]);
    vbf[d] = f2bf(values[i]);
}

// ---------------- Whh MFMA chunk: gates kt range [KT0,KT1); waves 8..15.
// wave widx owns jt = widx+8r (r<9) plus jt=72+widx for widx<3.
template<int KT0, int KT1>
__device__ __forceinline__ void whh_mfma(
    const u16* __restrict__ Wtbf, const u16* __restrict__ xh,
    const u16* __restrict__ xl, int widx, int ln, int lg, f32x4* gacc)
{
    constexpr int M = KT1 - KT0;
    bf16x8 ah[M], al[M];
    #pragma unroll
    for (int m = 0; m < M; ++m) {
        const int off = 128 + (KT0 - 4 + m) * 32 + lg * 8;
        ah[m] = *reinterpret_cast<const bf16x8*>(&xh[off]);
        al[m] = *reinterpret_cast<const bf16x8*>(&xl[off]);
    }
    #pragma unroll
    for (int r = 0; r < 9; ++r) {
        const u16* wt = Wtbf + ((size_t)((widx + 8 * r) * NKT) << 9) + (ln << 3);
        #pragma unroll
        for (int m = 0; m < M; ++m) {
            bf16x8 B = *reinterpret_cast<const bf16x8*>(wt + ((KT0 + m) << 9));
            gacc[r] = mfma16(ah[m], B, gacc[r]);
            gacc[r] = mfma16(al[m], B, gacc[r]);
        }
    }
    if (widx < 3) {
        const u16* wt = Wtbf + ((size_t)((72 + widx) * NKT) << 9) + (ln << 3);
        #pragma unroll
        for (int m = 0; m < M; ++m) {
            bf16x8 B = *reinterpret_cast<const bf16x8*>(wt + ((KT0 + m) << 9));
            gacc[9] = mfma16(ah[m], B, gacc[9]);
            gacc[9] = mfma16(al[m], B, gacc[9]);
        }
    }
}

// ---------------- logits: threads 64..195 (33 vocab x 4 lanes)
__device__ __forceinline__ void logits_fn(
    int tid, int b, int t, const float* __restrict__ projw,
    const float* __restrict__ projb, const float* __restrict__ h_s,
    const float* __restrict__ ctx_prev, float* __restrict__ out)
{
    const int idx = tid - 64;
    const int v = idx >> 2, l = idx & 3;
    const float* pw = projw + (size_t)v * KTOT;
    float s = 0.f;
    #pragma unroll 4
    for (int k = l; k < KTOT; k += 4)
        s += pw[k] * ((k < HIDD) ? h_s[k] : ctx_prev[k - HIDD]);
    s += __shfl_xor(s, 1);
    s += __shfl_xor(s, 2);
    if (l == 0)
        out[((size_t)t * BB + b) * NVOC + v] = s + projb[v];
}

// =====================================================================
__global__ void __launch_bounds__(1024, 4) decoder_v5(
    const int* __restrict__ input,
    const u16* __restrict__ kbf, const u16* __restrict__ vbf,
    const u16* __restrict__ phiH, const u16* __restrict__ phiL,
    const float* __restrict__ phi_b, const float* __restrict__ h0,
    const float* __restrict__ c0, const float* __restrict__ projw,
    const float* __restrict__ projb, const float* __restrict__ E2,
    const u16* __restrict__ Wtbf, float* __restrict__ out)
{
    const int tid = threadIdx.x;
    const int b = blockIdx.x;
    const int wv = tid >> 6, ln = tid & 63, lg = ln >> 4;
    const int widx = wv - 8;                 // G-wave index 0..7

    __shared__ float h_s[HIDD];
    __shared__ float c_s[HIDD];
    __shared__ float ctx2[2][VALD];
    __shared__ __align__(16) u16 xin_hi[448];    // [ctx 0..127 | h 128..427 | 0]
    __shared__ __align__(16) u16 xin_lo[448];
    __shared__ __align__(16) float glA[GDIM];    // Whh·h part
    __shared__ __align__(16) float glB[GDIM];    // Wctx·ctx part
    __shared__ __align__(16) float att[SS];
    __shared__ __align__(16) float q_s[KEYD];
    __shared__ __align__(16) float cpart[32][VALD];   // 16 KB
    __shared__ float pb_s[KEYD];
    __shared__ int xv_s;

    // ---- init
    for (int j = tid; j < HIDD; j += 1024) {
        float hv = h0[j];
        h_s[j] = hv;
        c_s[j] = c0[j];
        u16 hh, ll_; bf2term(hv, hh, ll_);
        xin_hi[128 + j] = hh; xin_lo[128 + j] = ll_;
    }
    if (tid < KEYD) pb_s[tid] = phi_b[tid];
    if (tid < 448 - KTOT) { xin_hi[KTOT + tid] = 0; xin_lo[KTOT + tid] = 0; }
    __syncthreads();

    f32x4 gacc[10];

    #pragma unroll 1
    for (int t = -1; t < TT; ++t) {
        // ---------- P0: cell(t) ----------
        if (t >= 0) {
            if (tid < HIDD) {
                const int j = tid;
                const float* e2r = E2 + (size_t)xv_s * GDIM;
                float s0 = glA[j]            + glB[j]            + e2r[j];
                float s1 = glA[HIDD + j]     + glB[HIDD + j]     + e2r[HIDD + j];
                float s2 = glA[2 * HIDD + j] + glB[2 * HIDD + j] + e2r[2 * HIDD + j];
                float s3 = glA[3 * HIDD + j] + glB[3 * HIDD + j] + e2r[3 * HIDD + j];
                float ig = sigmoidf_(s0);
                float fg = sigmoidf_(s1);
                float gt = tanh_f(s2);
                float og = sigmoidf_(s3);
                float cn = fg * c_s[j] + ig * gt;
                c_s[j] = cn;
                float hv = og * tanh_f(cn);
                h_s[j] = hv;
                u16 hh, ll_; bf2term(hv, hh, ll_);
                xin_hi[128 + j] = hh; xin_lo[128 + j] = ll_;
            }
            __syncthreads();
        }
        if (t == TT - 1) {   // final step: logits only
            if (tid >= 64 && tid < 196)
                logits_fn(tid, b, t, projw, projb, h_s, ctx2[(t + 1) & 1], out);
            break;
        }

        // ---------- P1: qpart MFMA (waves 0-7) || Whh kt4-6 (waves 8-15) ----
        if (wv < 8) {
            f32x4 qa = {0.f, 0.f, 0.f, 0.f};
            const u16* ph = phiH + ((size_t)(wv * 10) << 9) + (ln << 3);
            const u16* pl = phiL + ((size_t)(wv * 10) << 9) + (ln << 3);
            #pragma unroll
            for (int it = 0; it < 10; ++it) {
                bf16x8 Ah = *reinterpret_cast<const bf16x8*>(
                    &xin_hi[128 + it * 32 + lg * 8]);
                bf16x8 Al = *reinterpret_cast<const bf16x8*>(
                    &xin_lo[128 + it * 32 + lg * 8]);
                bf16x8 Bh = *reinterpret_cast<const bf16x8*>(ph + (it << 9));
                bf16x8 Bl = *reinterpret_cast<const bf16x8*>(pl + (it << 9));
                qa = mfma16(Ah, Bh, qa);
                qa = mfma16(Al, Bh, qa);
                qa = mfma16(Ah, Bl, qa);
            }
            if (ln < 16) q_s[wv * 16 + ln] = qa[0] + pb_s[wv * 16 + ln];
        } else {
            #pragma unroll
            for (int r = 0; r < 10; ++r) gacc[r] = (f32x4){0.f, 0.f, 0.f, 0.f};
            whh_mfma<4, 7>(Wtbf, xin_hi, xin_lo, widx, ln, lg, gacc);
            if (tid == 1023) xv_s = input[(t + 1) * BB + b];
        }
        __syncthreads();

        // ---------- P2: energy (waves 0-7, NT) || Whh kt7-9 ----------
        if (tid < 512) {
            const int l16 = tid & 15, sg = tid >> 4;
            const float4* q4 = reinterpret_cast<const float4*>(q_s);
            const float4 qa = q4[l16 * 2], qb = q4[l16 * 2 + 1];
            const u16* krow = kbf + ((size_t)b * SS) * KEYD;
            #pragma unroll 4
            for (int p = 0; p < 16; ++p) {
                int s = p * 32 + sg;
                const u32x4* kp = reinterpret_cast<const u32x4*>(
                    krow + (size_t)s * KEYD);
                u32x4 w = __builtin_nontemporal_load(kp + l16);
                float e = bflo(w.x) * qa.x + bfhi(w.x) * qa.y
                        + bflo(w.y) * qa.z + bfhi(w.y) * qa.w
                        + bflo(w.z) * qb.x + bfhi(w.z) * qb.y
                        + bflo(w.w) * qb.z + bfhi(w.w) * qb.w;
                e += __shfl_xor(e, 1);
                e += __shfl_xor(e, 2);
                e += __shfl_xor(e, 4);
                e += __shfl_xor(e, 8);
                if (l16 == 0) att[s] = e;
            }
        } else {
            whh_mfma<7, 10>(Wtbf, xin_hi, xin_lo, widx, ln, lg, gacc);
        }
        __syncthreads();

        // ---------- P3: softmax (wave0) || logits (thr 64-195) || Whh tail --
        if (tid < 64) {
            float4* a4 = reinterpret_cast<float4*>(att);
            float4 e0 = a4[tid * 2], e1 = a4[tid * 2 + 1];
            float m = fmaxf(fmaxf(fmaxf(e0.x, e0.y), fmaxf(e0.z, e0.w)),
                            fmaxf(fmaxf(e1.x, e1.y), fmaxf(e1.z, e1.w)));
            #pragma unroll
            for (int off = 32; off; off >>= 1) m = fmaxf(m, __shfl_xor(m, off));
            float p0 = __expf(e0.x - m), p1 = __expf(e0.y - m);
            float p2 = __expf(e0.z - m), p3 = __expf(e0.w - m);
            float p4 = __expf(e1.x - m), p5 = __expf(e1.y - m);
            float p6 = __expf(e1.z - m), p7 = __expf(e1.w - m);
            float ss = ((p0 + p1) + (p2 + p3)) + ((p4 + p5) + (p6 + p7));
            #pragma unroll
            for (int off = 32; off; off >>= 1) ss += __shfl_xor(ss, off);
            float inv = 1.f / ss;
            a4[tid * 2]     = make_float4(p0 * inv, p1 * inv, p2 * inv, p3 * inv);
            a4[tid * 2 + 1] = make_float4(p4 * inv, p5 * inv, p6 * inv, p7 * inv);
        } else if (tid < 196) {
            if (t >= 0)
                logits_fn(tid, b, t, projw, projb, h_s, ctx2[(t + 1) & 1], out);
        } else if (wv >= 8) {
            whh_mfma<10, 14>(Wtbf, xin_hi, xin_lo, widx, ln, lg, gacc);
            if (ln < 16) {
                #pragma unroll
                for (int r = 0; r < 9; ++r)
                    glA[(widx + 8 * r) * 16 + ln] = gacc[r][0];
                if (widx < 3) glA[(72 + widx) * 16 + ln] = gacc[9][0];
            }
        }
        __syncthreads();

        // ---------- P4: PV (all 1024, NT) ----------
        {
            const int v4 = tid & 31, sg = tid >> 5;
            float4 a = make_float4(0.f, 0.f, 0.f, 0.f);
            const u16* vrow = vbf + ((size_t)b * SS) * VALD;
            #pragma unroll 4
            for (int i = 0; i < 16; ++i) {
                int s = sg * 16 + i;
                const u32x2* vp = reinterpret_cast<const u32x2*>(
                    vrow + (size_t)s * VALD);
                u32x2 w = __builtin_nontemporal_load(vp + v4);
                float wt = att[s];
                a.x += wt * bflo(w.x); a.y += wt * bfhi(w.x);
                a.z += wt * bflo(w.y); a.w += wt * bfhi(w.y);
            }
            *reinterpret_cast<float4*>(&cpart[sg][v4 * 4]) = a;
        }
        __syncthreads();

        // ---------- P5: ctx reduce -> ctx2, xin hi/lo ----------
        if (tid < VALD) {
            float s = 0.f;
            #pragma unroll
            for (int g = 0; g < 32; ++g) s += cpart[g][tid];
            ctx2[t & 1][tid] = s;
            u16 hh, ll_; bf2term(s, hh, ll_);
            xin_hi[tid] = hh; xin_lo[tid] = ll_;
        }
        __syncthreads();

        // ---------- P6: Wctx MFMA (all 16 waves) -> glB ----------
        {
            bf16x8 ch[4], cl[4];
            #pragma unroll
            for (int m = 0; m < 4; ++m) {
                ch[m] = *reinterpret_cast<const bf16x8*>(&xin_hi[m * 32 + lg * 8]);
                cl[m] = *reinterpret_cast<const bf16x8*>(&xin_lo[m * 32 + lg * 8]);
            }
            #pragma unroll
            for (int r = 0; r < 4; ++r) {
                const int jt = wv + 16 * r;
                const u16* wt = Wtbf + ((size_t)(jt * NKT) << 9) + (ln << 3);
                f32x4 acc = {0.f, 0.f, 0.f, 0.f};
                #pragma unroll
                for (int m = 0; m < 4; ++m) {
                    bf16x8 B = *reinterpret_cast<const bf16x8*>(wt + (m << 9));
                    acc = mfma16(ch[m], B, acc);
                    acc = mfma16(cl[m], B, acc);
                }
                if (ln < 16) glB[jt * 16 + ln] = acc[0];
            }
            if (wv < 11) {
                const int jt = wv + 64;
                const u16* wt = Wtbf + ((size_t)(jt * NKT) << 9) + (ln << 3);
                f32x4 acc = {0.f, 0.f, 0.f, 0.f};
                #pragma unroll
                for (int m = 0; m < 4; ++m) {
                    bf16x8 B = *reinterpret_cast<const bf16x8*>(wt + (m << 9));
                    acc = mfma16(ch[m], B, acc);
                    acc = mfma16(cl[m], B, acc);
                }
                if (ln < 16) glB[jt * 16 + ln] = acc[0];
            }
        }
        __syncthreads();
    }
}

// =====================================================================
extern "C" void kernel_launch(void* const* d_in, const int* in_sizes, int n_in,
                              void* d_out, int out_size, void* d_ws, size_t ws_size,
                              hipStream_t stream)
{
    const int*   input     = (const int*)  d_in[0];
    const float* keys      = (const float*)d_in[1];
    const float* values    = (const float*)d_in[2];
    const float* embedding = (const float*)d_in[3];
    const float* phi_w     = (const float*)d_in[4];
    const float* phi_b     = (const float*)d_in[5];
    const float* h0        = (const float*)d_in[6];
    const float* c0        = (const float*)d_in[7];
    const float* W_ih      = (const float*)d_in[8];
    const float* b_ih      = (const float*)d_in[9];
    const float* W_hh      = (const float*)d_in[10];
    const float* b_hh      = (const float*)d_in[11];
    const float* proj_w    = (const float*)d_in[12];
    const float* proj_b    = (const float*)d_in[13];
    float* out = (float*)d_out;

    char* base = (char*)d_ws;
    size_t off = 0;
    auto alloc = [&](size_t bytes) {
        size_t o = off;
        off = (off + bytes + 255) & ~(size_t)255;
        return o;
    };
    size_t oE2   = alloc((size_t)NVOC * GDIM * 4);        // 158 KB
    size_t oPhiH = alloc((size_t)8 * 10 * 512 * 2);       // 80 KB
    size_t oPhiL = alloc((size_t)8 * 10 * 512 * 2);       // 80 KB
    size_t oWtb  = alloc((size_t)NJT * NKT * 512 * 2);    // 1.05 MB
    size_t oKbf  = alloc((size_t)SS * BB * KEYD * 2);     // 33.6 MB
    size_t oVbf  = alloc((size_t)SS * BB * VALD * 2);     // 33.6 MB
    (void)off;

    float* E2 = (float*)(base + oE2);
    u16* phiH = (u16*)(base + oPhiH);
    u16* phiL = (u16*)(base + oPhiL);
    u16* Wtbf = (u16*)(base + oWtb);
    u16* kbf  = (u16*)(base + oKbf);
    u16* vbf  = (u16*)(base + oVbf);

    p_e2<<<NVOC, 256, 0, stream>>>(embedding, W_ih, b_ih, b_hh, E2);
    p_wt<<<2048, 256, 0, stream>>>(W_ih, W_hh, phi_w, Wtbf, phiH, phiL);
    p_kv<<<(SS * BB * KEYD) / 1024, 1024, 0, stream>>>(keys, values, kbf, vbf);

    decoder_v5<<<NBLK, 1024, 0, stream>>>(
        input, kbf, vbf, phiH, phiL, phi_b, h0, c0,
        proj_w, proj_b, E2, Wtbf, out);
}

// Round 8
// 6382.155 us; speedup vs baseline: 3.2467x; 3.2467x over previous
//
#include <hip/hip_runtime.h>
#include <math.h>

// Problem constants
#define EMBD 400
#define HIDD 300
#define KEYD 128
#define VALD 128
#define NVOC 33
#define TT 256
#define BB 256
#define SS 512
#define WIH_LD 528          // EMB+VAL
#define GDIM 1200           // 4*HID
#define KTOT 428            // ctx(128)+h(300)
#define KPAD 432            // padded
#define NK2 216             // KPAD/2 (k-pairs)
#define NI2 152             // padded phi i-pairs (150 real + 2 zero)
#define NBLK 256            // one block per batch row

typedef unsigned int u32;
typedef unsigned int u32x4 __attribute__((ext_vector_type(4)));
typedef _Float16 f16x2 __attribute__((ext_vector_type(2)));

__device__ __forceinline__ f16x2 h2u(u32 u) {
    return __builtin_bit_cast(f16x2, u);
}
__device__ __forceinline__ float fdot2_(u32 w, f16x2 x, float c) {
    return __builtin_amdgcn_fdot2(h2u(w), x, c, false);
}
__device__ __forceinline__ float sigmoidf_(float x) {
    return 1.f / (1.f + __expf(-x));
}
__device__ __forceinline__ float tanh_f(float x) {
    float ax = fabsf(x);
    if (ax > 15.f) return x > 0.f ? 1.f : -1.f;
    float e = __expf(2.f * x);
    return (e - 1.f) / (e + 1.f);
}

// ---------------- Precompute: E2[v][j] = b_ih[j]+b_hh[j]+emb[v]·W_ih[j][:400]
__global__ __launch_bounds__(256) void p_e2(
    const float* __restrict__ emb, const float* __restrict__ Wih,
    const float* __restrict__ bih, const float* __restrict__ bhh,
    float* __restrict__ E2)
{
    __shared__ float es[EMBD];
    const int v = blockIdx.x;
    for (int i = threadIdx.x; i < EMBD; i += 256) es[i] = emb[v * EMBD + i];
    __syncthreads();
    for (int j = threadIdx.x; j < GDIM; j += 256) {
        const float* wr = &Wih[(size_t)j * WIH_LD];
        float s0 = 0.f, s1 = 0.f, s2 = 0.f, s3 = 0.f;
        for (int e = 0; e < EMBD; e += 4) {
            s0 += es[e]     * wr[e];
            s1 += es[e + 1] * wr[e + 1];
            s2 += es[e + 2] * wr[e + 2];
            s3 += es[e + 3] * wr[e + 3];
        }
        E2[v * GDIM + j] = bih[j] + bhh[j] + ((s0 + s1) + (s2 + s3));
    }
}

// ---------------- Precompute: W2[k2][j] = pack_f16(W[2k2][j], W[2k2+1][j]);
// phi2[i2][k] = pack_f16(phi_w[k][2i2], phi_w[k][2i2+1])
__global__ __launch_bounds__(256) void p_w2(
    const float* __restrict__ Wih, const float* __restrict__ Whh,
    const float* __restrict__ phi_w,
    u32* __restrict__ W2, u32* __restrict__ phi2)
{
    const int stride = gridDim.x * 256;
    const int tot1 = NK2 * GDIM;
    for (int m = blockIdx.x * 256 + threadIdx.x; m < tot1; m += stride) {
        int k2 = m / GDIM, j = m - k2 * GDIM;
        float w0 = 0.f, w1 = 0.f;
        int k0 = 2 * k2, k1 = 2 * k2 + 1;
        if (k0 < KEYD)      w0 = Wih[(size_t)j * WIH_LD + EMBD + k0];
        else if (k0 < KTOT) w0 = Whh[(size_t)j * HIDD + (k0 - KEYD)];
        if (k1 < KEYD)      w1 = Wih[(size_t)j * WIH_LD + EMBD + k1];
        else if (k1 < KTOT) w1 = Whh[(size_t)j * HIDD + (k1 - KEYD)];
        f16x2 p; p[0] = (_Float16)w0; p[1] = (_Float16)w1;
        W2[m] = __builtin_bit_cast(u32, p);
    }
    const int tot2 = NI2 * KEYD;
    for (int m = blockIdx.x * 256 + threadIdx.x; m < tot2; m += stride) {
        int i2 = m >> 7, k = m & 127;
        float w0 = 0.f, w1 = 0.f;
        if (2 * i2 < HIDD)     w0 = phi_w[(size_t)k * HIDD + 2 * i2];
        if (2 * i2 + 1 < HIDD) w1 = phi_w[(size_t)k * HIDD + 2 * i2 + 1];
        f16x2 p; p[0] = (_Float16)w0; p[1] = (_Float16)w1;
        phi2[m] = __builtin_bit_cast(u32, p);
    }
}

// ---------------- Precompute: K -> f16 [b][s][d]; V -> f16 pairs [b][s2][d][2]
__global__ __launch_bounds__(1024) void p_kv(
    const float* __restrict__ keys, const float* __restrict__ values,
    _Float16* __restrict__ kh, _Float16* __restrict__ vh2)
{
    size_t i = (size_t)blockIdx.x * 1024 + threadIdx.x;  // S*B*128 exactly
    int s = (int)(i >> 15);
    int r = (int)(i & 32767);
    int b = r >> 7, d = r & 127;
    kh[(((size_t)b * SS + s) << 7) + d] = (_Float16)keys[i];
    size_t vd = ((((size_t)b * 256 + (s >> 1)) << 7) + d) * 2 + (s & 1);
    vh2[vd] = (_Float16)values[i];
}

// ---------------- logits: threads 512..1023; 16 lanes per vocab, f32
__device__ __forceinline__ void logits33(
    int tid, int b, int t, const float* __restrict__ projw,
    const float* __restrict__ projb, float* __restrict__ out,
    const float* __restrict__ h_s, const float* __restrict__ ctx_s)
{
    if (tid >= 512) {
        const int idx = tid - 512;
        const int l = idx & 15;
        const int vs = idx >> 4;                  // 0..31
        #pragma unroll
        for (int rep = 0; rep < 2; ++rep) {
            const int v = vs + rep * 32;
            if (v < NVOC) {
                const float* pw = projw + (size_t)v * KTOT;
                float s = 0.f;
                for (int k = l; k < KTOT; k += 16) {
                    float u = (k < HIDD) ? h_s[k] : ctx_s[k - HIDD];
                    s += pw[k] * u;
                }
                #pragma unroll
                for (int off = 8; off; off >>= 1) s += __shfl_xor(s, off);
                if (l == 0)
                    out[((size_t)t * BB + b) * NVOC + v] = s + projb[v];
            }
        }
    }
}

// ---------------- attend for one row (1024 threads), f16 dot2 paths.
// OVL: overlap logits(t) on upper 512 during q-partial phase.
template<int OVL>
__device__ __forceinline__ void attend1(
    const int tid, const int b, const int t,
    const _Float16* __restrict__ kh, const _Float16* __restrict__ vh2,
    const u32* __restrict__ phi2, const float* __restrict__ phi_b,
    const float* __restrict__ projw, const float* __restrict__ projb,
    float* __restrict__ out,
    float* h_s, float* ctx_s, float* q_s, float* att, _Float16* att_h,
    float (*qp)[KEYD], float (*cpart)[VALD], float* redM, float* redS,
    _Float16* xinh, const u32* xin2)
{
    // ---- q partial: q[k] = sum_i h[i]*phi[i][k]; lower 512 (4 i2-slices of 38)
    if (tid < 512) {
        const int k = tid & 127, sl = tid >> 7;
        const int i20 = sl * 38;
        float acc = 0.f;
        #pragma unroll 19
        for (int i2 = i20; i2 < i20 + 38; ++i2)
            acc = fdot2_(phi2[i2 * 128 + k], h2u(xin2[64 + i2]), acc);
        qp[sl][k] = acc;
    } else if (OVL) {
        logits33(tid, b, t, projw, projb, out, h_s, ctx_s);
    }
    __syncthreads();
    if (tid < KEYD)
        q_s[tid] = phi_b[tid] + qp[0][tid] + qp[1][tid] + qp[2][tid] + qp[3][tid];
    __syncthreads();

    // ---- energy: 64 s-groups x 16 lanes; 8 s per group; f16 dot2
    {
        const int l16 = tid & 15, sg = tid >> 4;    // sg 0..63
        const float4* q4 = reinterpret_cast<const float4*>(q_s);
        const float4 qa = q4[l16 * 2], qb = q4[l16 * 2 + 1];
        f16x2 q2a, q2b, q2c, q2d;
        q2a[0] = (_Float16)qa.x; q2a[1] = (_Float16)qa.y;
        q2b[0] = (_Float16)qa.z; q2b[1] = (_Float16)qa.w;
        q2c[0] = (_Float16)qb.x; q2c[1] = (_Float16)qb.y;
        q2d[0] = (_Float16)qb.z; q2d[1] = (_Float16)qb.w;
        const _Float16* krow = kh + (((size_t)b * SS) << 7);
        #pragma unroll
        for (int p = 0; p < 8; ++p) {
            int s = p * 64 + sg;
            const u32x4* kp = reinterpret_cast<const u32x4*>(krow + ((size_t)s << 7));
            u32x4 w = __builtin_nontemporal_load(kp + l16);
            float e = fdot2_(w.x, q2a, 0.f);
            e = fdot2_(w.y, q2b, e);
            e = fdot2_(w.z, q2c, e);
            e = fdot2_(w.w, q2d, e);
            e += __shfl_xor(e, 1);
            e += __shfl_xor(e, 2);
            e += __shfl_xor(e, 4);
            e += __shfl_xor(e, 8);
            if (l16 == 0) att[s] = e;
        }
    }
    __syncthreads();

    // ---- softmax over 512 energies (threads 0..511 own one each)
    {
        const int lane = tid & 63, wv = tid >> 6;
        float e0 = (tid < 512) ? att[tid] : -1e30f;
        float m = e0;
        #pragma unroll
        for (int off = 32; off; off >>= 1) m = fmaxf(m, __shfl_xor(m, off));
        if (tid < 512 && lane == 0) redM[wv] = m;
        __syncthreads();
        float M = redM[0];
        #pragma unroll
        for (int w = 1; w < 8; ++w) M = fmaxf(M, redM[w]);
        float p0 = (tid < 512) ? __expf(e0 - M) : 0.f;
        float ss = p0;
        #pragma unroll
        for (int off = 32; off; off >>= 1) ss += __shfl_xor(ss, off);
        if (tid < 512 && lane == 0) redS[wv] = ss;
        __syncthreads();
        float inv = 1.f / (redS[0] + redS[1] + redS[2] + redS[3]
                         + redS[4] + redS[5] + redS[6] + redS[7]);
        if (tid < 512) {
            float pv = p0 * inv;
            att[tid] = pv;
            att_h[tid] = (_Float16)pv;
        }
    }
    __syncthreads();

    // ---- ctx[d] = sum_s att[s]*V[s][d]: 32 s2-groups x 32 lanes, f16 dot2
    {
        const int v4 = tid & 31, sg = tid >> 5;     // sg 0..31
        float4 a = make_float4(0.f, 0.f, 0.f, 0.f);
        const u32* vrow = reinterpret_cast<const u32*>(vh2) + (((size_t)b * 256) << 7);
        const u32* att2 = reinterpret_cast<const u32*>(att_h);
        #pragma unroll
        for (int i = 0; i < 8; ++i) {
            int s2 = sg * 8 + i;
            f16x2 wt2 = h2u(att2[s2]);
            const u32x4* vp = reinterpret_cast<const u32x4*>(vrow + ((size_t)s2 << 7));
            u32x4 w = __builtin_nontemporal_load(vp + v4);
            a.x = fdot2_(w.x, wt2, a.x);
            a.y = fdot2_(w.y, wt2, a.y);
            a.z = fdot2_(w.z, wt2, a.z);
            a.w = fdot2_(w.w, wt2, a.w);
        }
        *reinterpret_cast<float4*>(&cpart[sg][v4 * 4]) = a;
    }
    __syncthreads();
    if (tid < VALD) {
        float s = 0.f;
        #pragma unroll
        for (int g = 0; g < 32; ++g) s += cpart[g][tid];
        ctx_s[tid] = s;
        xinh[tid] = (_Float16)s;       // staged for next gates GEMM
    }
    __syncthreads();
}

// ---------------- main body: one persistent block per batch row ------------
__global__ void __launch_bounds__(1024, 4) decoder_dot(
    const int* __restrict__ input,
    const _Float16* __restrict__ kh, const _Float16* __restrict__ vh2,
    const u32* __restrict__ phi2, const float* __restrict__ phi_b,
    const float* __restrict__ h0, const float* __restrict__ c0,
    const float* __restrict__ projw, const float* __restrict__ projb,
    const float* __restrict__ E2, const u32* __restrict__ W2,
    float* __restrict__ out)
{
    const int tid = threadIdx.x;
    const int b = blockIdx.x;

    __shared__ float h_s[HIDD];
    __shared__ float c_s[HIDD];
    __shared__ float ctx_s[VALD];
    __shared__ __align__(16) _Float16 xinh[448];     // [ctx 0..127|h 128..427|0]
    __shared__ __align__(16) float gp[3 * GDIM];     // 3 k-slice partials
    __shared__ __align__(16) float att[SS];
    __shared__ __align__(16) _Float16 att_h[SS];
    __shared__ __align__(16) float q_s[KEYD];
    __shared__ __align__(16) float qp[4][KEYD];
    __shared__ __align__(16) float cpart[32][VALD];  // 16 KB
    __shared__ float redM[8], redS[8];
    __shared__ int xv_s;

    const u32* xin2 = reinterpret_cast<const u32*>(xinh);

    // ---- init h, c, xinh-h part, pad
    for (int j = tid; j < HIDD; j += 1024) {
        float hv = h0[j];
        h_s[j] = hv;
        c_s[j] = c0[j];
        xinh[VALD + j] = (_Float16)hv;
    }
    if (tid < 448 - KTOT) xinh[KTOT + tid] = (_Float16)0.f;
    __syncthreads();

    // ctx(-1) = attend(h_init); no logits overlap
    attend1<0>(tid, b, 0, kh, vh2, phi2, phi_b, projw, projb, out,
               h_s, ctx_s, q_s, att, att_h, qp, cpart, redM, redS, xinh, xin2);

    #pragma unroll 1
    for (int t = 0; t < TT; ++t) {
        // ---- gates GEMM: gl[j] = sum_k xin[k]*W[k][j] via f16 dot2.
        // 900 workers: 300 j-quads x 3 k2-slices of 72.
        if (tid < 900) {
            const int c = tid / 300;
            const int q = tid - c * 300;
            const u32* Wp = W2 + (size_t)(c * 72) * GDIM + 4 * q;
            const u32* xp = xin2 + c * 72;
            float a0 = 0.f, a1 = 0.f, a2 = 0.f, a3 = 0.f;
            #pragma unroll 8
            for (int k2 = 0; k2 < 72; ++k2) {
                f16x2 x2 = h2u(xp[k2]);
                u32x4 w = *reinterpret_cast<const u32x4*>(Wp + (size_t)k2 * GDIM);
                a0 = fdot2_(w.x, x2, a0);
                a1 = fdot2_(w.y, x2, a1);
                a2 = fdot2_(w.z, x2, a2);
                a3 = fdot2_(w.w, x2, a3);
            }
            reinterpret_cast<float4*>(gp + c * GDIM)[q] =
                make_float4(a0, a1, a2, a3);
        } else if (tid == 1023) {
            xv_s = input[t * BB + b];
        }
        __syncthreads();

        // ---- cell update (+E2 embedding gather); 300 threads, one j each
        if (tid < HIDD) {
            const int j = tid;
            const float* e2r = E2 + (size_t)xv_s * GDIM;
            float gi = gp[j]
                     + gp[GDIM + j]
                     + gp[2 * GDIM + j]            + e2r[j];
            float gf = gp[HIDD + j]
                     + gp[GDIM + HIDD + j]
                     + gp[2 * GDIM + HIDD + j]     + e2r[HIDD + j];
            float gg = gp[2 * HIDD + j]
                     + gp[GDIM + 2 * HIDD + j]
                     + gp[2 * GDIM + 2 * HIDD + j] + e2r[2 * HIDD + j];
            float go = gp[3 * HIDD + j]
                     + gp[GDIM + 3 * HIDD + j]
                     + gp[2 * GDIM + 3 * HIDD + j] + e2r[3 * HIDD + j];
            float ig = sigmoidf_(gi);
            float fg = sigmoidf_(gf);
            float gt = tanh_f(gg);
            float og = sigmoidf_(go);
            float cn = fg * c_s[j] + ig * gt;
            c_s[j] = cn;
            float hv = og * tanh_f(cn);
            h_s[j] = hv;
            xinh[VALD + j] = (_Float16)hv;
        }
        __syncthreads();

        // ---- attend(h(t)) -> ctx(t), logits(t) overlapped on upper 512.
        if (t < TT - 1) {
            attend1<1>(tid, b, t, kh, vh2, phi2, phi_b, projw, projb, out,
                       h_s, ctx_s, q_s, att, att_h, qp, cpart, redM, redS,
                       xinh, xin2);
        } else {
            logits33(tid, b, t, projw, projb, out, h_s, ctx_s);
        }
    }
}

// =====================================================================
extern "C" void kernel_launch(void* const* d_in, const int* in_sizes, int n_in,
                              void* d_out, int out_size, void* d_ws, size_t ws_size,
                              hipStream_t stream)
{
    const int*   input     = (const int*)  d_in[0];
    const float* keys      = (const float*)d_in[1];
    const float* values    = (const float*)d_in[2];
    const float* embedding = (const float*)d_in[3];
    const float* phi_w     = (const float*)d_in[4];
    const float* phi_b     = (const float*)d_in[5];
    const float* h0        = (const float*)d_in[6];
    const float* c0        = (const float*)d_in[7];
    const float* W_ih      = (const float*)d_in[8];
    const float* b_ih      = (const float*)d_in[9];
    const float* W_hh      = (const float*)d_in[10];
    const float* b_hh      = (const float*)d_in[11];
    const float* proj_w    = (const float*)d_in[12];
    const float* proj_b    = (const float*)d_in[13];
    float* out = (float*)d_out;

    char* base = (char*)d_ws;
    size_t off = 0;
    auto alloc = [&](size_t bytes) {
        size_t o = off;
        off = (off + bytes + 255) & ~(size_t)255;
        return o;
    };
    size_t oE2   = alloc((size_t)NVOC * GDIM * 4);       // 158 KB
    size_t oPhi  = alloc((size_t)NI2 * KEYD * 4);        // 78 KB
    size_t oW2   = alloc((size_t)NK2 * GDIM * 4);        // 1.04 MB
    size_t oKh   = alloc((size_t)BB * SS * KEYD * 2);    // 33.6 MB
    size_t oVh   = alloc((size_t)BB * SS * VALD * 2);    // 33.6 MB
    (void)off;

    float* E2    = (float*)(base + oE2);
    u32* phi2    = (u32*)(base + oPhi);
    u32* W2      = (u32*)(base + oW2);
    _Float16* kh = (_Float16*)(base + oKh);
    _Float16* vh2= (_Float16*)(base + oVh);

    p_e2<<<NVOC, 256, 0, stream>>>(embedding, W_ih, b_ih, b_hh, E2);
    p_w2<<<2048, 256, 0, stream>>>(W_ih, W_hh, phi_w, W2, phi2);
    p_kv<<<(SS * BB * KEYD) / 1024, 1024, 0, stream>>>(keys, values, kh, vh2);

    decoder_dot<<<NBLK, 1024, 0, stream>>>(
        input, kh, vh2, phi2, phi_b, h0, c0,
        proj_w, proj_b, E2, W2, out);
}